// Round 1
// 589.524 us; speedup vs baseline: 1.0308x; 1.0308x over previous
//
#include <hip/hip_runtime.h>
#include <hip/hip_bf16.h>

// B=4,H=8,N=2048,DV=64. BH=32.
// P_d = stable argsort of v[:,d] (per bh), Q_d = inverse perm (rank), vs_d = sorted col.
// out[r,d] = vs_d[ Q_{(d+1)%64}[r] ]
// attn[r,:] = one_hot( P_0[ Q_1[r] ] )
//
// ws: Q ushort[32*64*2048] (8MB) | vs float[32*64*2048] (16MB) | P0 ushort[32*2048]
// d_out scratch: outT (16MB) and vT (16MB) live inside the attn region; both are
// fully consumed before attn_kernel overwrites the region.
//
// Sort replaced by exact bucket-rank: monotone linear map -> 2048-bucket LDS
// histogram -> scan -> scatter -> exact within-bucket (key,idx) rank.
// Exact & stable for ANY input (distribution only affects the inner-loop length).

#define SORT_N 2048
#define NBH 32
#define NDV 64
#define SLOT(i)  ((i) + ((i) >> 3))   // u64 pad: breaks 64B-stride bank aliasing
#define HS(i)    ((i) + ((i) >> 5))   // u32 pad for the histogram array

// ---------------- Kernel 0: v transpose (coalesced column loads) ------------
__global__ __launch_bounds__(256) void v_transpose_kernel(
    const float* __restrict__ v, float* __restrict__ vT) {
  __shared__ float tile[64][65];
  const int blk = blockIdx.x;        // bh*32 + rtile
  const int bh = blk >> 5;
  const int r0 = (blk & 31) << 6;
  const int tx = threadIdx.x & 63;
  const int ty = threadIdx.x >> 6;   // 0..3
  for (int i = ty; i < 64; i += 4)   // read v[bh][r0+i][tx] coalesced
    tile[i][tx] = v[((size_t)((bh << 11) + r0 + i) << 6) + tx];
  __syncthreads();
  for (int i = ty; i < 64; i += 4)   // write vT[bh][i][r0+tx] coalesced
    vT[((size_t)((bh << 6) + i) << 11) + r0 + tx] = tile[tx][i];
}

// ---------------- Kernel 1: exact bucket-rank per column --------------------
// One WG per (bh,d) column. Thread t owns original indices {t+256e, e=0..7}.
__global__ __launch_bounds__(256) void rank_kernel(
    const float* __restrict__ vT, unsigned short* __restrict__ Q,
    float* __restrict__ vs, unsigned short* __restrict__ P0) {
  const int col = blockIdx.x;        // bh*64 + d
  const int bh  = col >> 6;
  const int d   = col & 63;
  const float* vcol = vT + ((size_t)col << 11);

  __shared__ unsigned base[2112];                       // HS-padded 2048 bins
  __shared__ unsigned long long bkt[SORT_N + 256];      // SLOT-padded scatter
  __shared__ float vsorted[SORT_N];
  __shared__ unsigned wsum[4];

  const int t = threadIdx.x;

  float x[8]; unsigned key[8]; int bk[8];
#pragma unroll
  for (int e = 0; e < 8; ++e) {
    float f = vcol[t + (e << 8)];                       // coalesced
    x[e] = f;
    unsigned u = __float_as_uint(f);
    key[e] = (u & 0x80000000u) ? ~u : (u | 0x80000000u);  // order-preserving bias
    // monotone bucket map: range [-2.75, 2.75] -> [0, 2048)
    float tb = fmaf(f, 372.3636f, 1024.0f);
    tb = fminf(fmaxf(tb, 0.0f), 2047.0f);
    bk[e] = (int)tb;                                    // trunc == floor (tb >= 0)
  }

  // zero histogram (incl. pad slots)
  for (int i = t; i < 2112; i += 256) base[i] = 0;
  __syncthreads();
#pragma unroll
  for (int e = 0; e < 8; ++e) atomicAdd(&base[HS(bk[e])], 1u);
  __syncthreads();

  // block exclusive scan over the 2048 bins (thread t owns bins 8t..8t+7)
  unsigned c[8];
#pragma unroll
  for (int e = 0; e < 8; ++e) c[e] = base[HS((t << 3) + e)];
  unsigned s = 0;
#pragma unroll
  for (int e = 0; e < 8; ++e) s += c[e];
  unsigned incl = s;
  for (int off = 1; off < 64; off <<= 1) {
    unsigned tmp = __shfl_up(incl, off);
    if ((t & 63) >= off) incl += tmp;
  }
  const int w = t >> 6;
  if ((t & 63) == 63) wsum[w] = incl;
  __syncthreads();
  unsigned run = incl - s;                              // exclusive within wave
  for (int i = 0; i < w; ++i) run += wsum[i];           // + earlier waves
#pragma unroll
  for (int e = 0; e < 8; ++e) {                         // own slots only: no race
    unsigned cc = c[e];
    base[HS((t << 3) + e)] = run;                       // exclusive bucket base
    run += cc;
  }
  __syncthreads();

  // scatter (key<<32|idx) into bucketed order (arbitrary order within bucket)
#pragma unroll
  for (int e = 0; e < 8; ++e) {
    unsigned idx = (unsigned)(t + (e << 8));
    unsigned long long me = ((unsigned long long)key[e] << 32) | idx;
    unsigned pos = atomicAdd(&base[HS(bk[e])], 1u);     // base[b] becomes bucket end
    bkt[SLOT(pos)] = me;
  }
  __syncthreads();

  // exact rank = bucket start + #{strictly smaller (key,idx) in bucket}
  unsigned short* Qcol = Q + ((size_t)col << 11);
  float* vscol = vs + ((size_t)col << 11);
#pragma unroll
  for (int e = 0; e < 8; ++e) {
    unsigned idx = (unsigned)(t + (e << 8));
    const int b = bk[e];
    unsigned end   = base[HS(b)];                       // post-scatter = bucket end
    unsigned start = (b == 0) ? 0u : base[HS(b - 1)];   // end of prev = my start
    unsigned long long me = ((unsigned long long)key[e] << 32) | idx;
    unsigned r = start;
    for (unsigned p = start; p < end; ++p)
      r += (bkt[SLOT(p)] < me) ? 1u : 0u;
    Qcol[idx] = (unsigned short)r;                      // coalesced ushort write
    vsorted[r] = x[e];                                  // LDS scatter
    if (d == 0) P0[((size_t)bh << 11) + r] = (unsigned short)idx;
  }
  __syncthreads();
#pragma unroll
  for (int e = 0; e < 8; ++e) {                         // coalesced vs write
    int rr = t + (e << 8);
    vscol[rr] = vsorted[rr];
  }
}

// ------- Kernel 2a: outT[(bh,d)][r] = vs_d[Q_{d+1}[r]]  (all coalesced) -----
__global__ __launch_bounds__(256) void out_colT_kernel(
    const unsigned short* __restrict__ Q, const float* __restrict__ vs,
    float* __restrict__ outT) {
  const int b  = blockIdx.x;         // bh*64 + d
  const int bh = b >> 6;
  const int d  = b & 63;
  const int dn = (d + 1) & 63;
  const int t  = threadIdx.x;

  __shared__ float col[SORT_N];      // 8 KiB
  const float* vcol = vs + ((size_t)b << 11);
  for (int r = t; r < SORT_N; r += 256) col[r] = vcol[r];   // coalesced
  __syncthreads();

  const unsigned short* Qcol = Q + ((size_t)((bh << 6) + dn) << 11);
  float* ocol = outT + ((size_t)b << 11);
  for (int r = t; r < SORT_N; r += 256) {
    int q = Qcol[r];                 // coalesced ushort read
    ocol[r] = col[q];                // LDS gather + coalesced write
  }
}

// ------- Kernel 2b: out[r][d] = outT[d][r]  (64x64 LDS tile transpose) ------
__global__ __launch_bounds__(256) void out_transpose_kernel(
    const float* __restrict__ outT, float* __restrict__ out) {
  __shared__ float tile[64][65];     // +1 pad breaks bank conflicts
  const int blk = blockIdx.x;        // bh*32 + rtile
  const int bh = blk >> 5;
  const int r0 = (blk & 31) << 6;    // 64-row tile
  const int tx = threadIdx.x & 63;
  const int ty = threadIdx.x >> 6;   // 0..3

  for (int i = ty; i < 64; i += 4)   // read outT[d=i][r0+tx] coalesced
    tile[i][tx] = outT[(((size_t)(bh << 6) + i) << 11) + r0 + tx];
  __syncthreads();
  for (int i = ty; i < 64; i += 4)   // write out[r0+i][d=tx] coalesced
    out[(((size_t)(bh << 11) + r0 + i) << 6) + tx] = tile[tx][i];
}

// ---------------- Kernel 3: attn rows, fused zero + one-hot -----------------
__global__ __launch_bounds__(256) void attn_kernel(
    const unsigned short* __restrict__ P0, const unsigned short* __restrict__ Q,
    float* __restrict__ attn) {
  int row = blockIdx.x;              // bh*2048 + r
  int bh = row >> 11;
  int r  = row & 2047;
  int q   = Q[(((bh << 6) + 1) << 11) + r];   // Q_1[r]
  int idx = P0[(bh << 11) + q];               // P_0[Q_1[r]]
  float4* rowp = (float4*)(attn + (size_t)row * SORT_N);
  int t = threadIdx.x;
#pragma unroll
  for (int it = 0; it < 2; ++it) {
    int f4 = t + it * 256;
    int basei = f4 * 4;
    float4 val;
    val.x = (basei + 0 == idx) ? 1.0f : 0.0f;
    val.y = (basei + 1 == idx) ? 1.0f : 0.0f;
    val.z = (basei + 2 == idx) ? 1.0f : 0.0f;
    val.w = (basei + 3 == idx) ? 1.0f : 0.0f;
    rowp[f4] = val;
  }
}

extern "C" void kernel_launch(void* const* d_in, const int* in_sizes, int n_in,
                              void* d_out, int out_size, void* d_ws, size_t ws_size,
                              hipStream_t stream) {
  const float* v = (const float*)d_in[2];     // q,k unused by reference
  float* out  = (float*)d_out;
  float* attn = out + (size_t)NBH * SORT_N * NDV;
  // scratch inside the attn region (536MB); both consumed before attn_kernel:
  float* outT = attn;                                   // 16MB
  float* vT   = attn + (size_t)NBH * SORT_N * NDV;      // next 16MB

  unsigned short* Q  = (unsigned short*)d_ws;                             // 8 MiB
  float* vs          = (float*)((char*)d_ws + (size_t)8 * 1024 * 1024);   // 16 MiB
  unsigned short* P0 = (unsigned short*)((char*)d_ws + (size_t)24 * 1024 * 1024);

  v_transpose_kernel<<<NBH * 32, 256, 0, stream>>>(v, vT);
  rank_kernel<<<NBH * NDV, 256, 0, stream>>>(vT, Q, vs, P0);
  out_colT_kernel<<<NBH * NDV, 256, 0, stream>>>(Q, vs, outT);
  out_transpose_kernel<<<NBH * 32, 256, 0, stream>>>(outT, out);
  attn_kernel<<<NBH * SORT_N, 256, 0, stream>>>(P0, Q, attn);
}